// Round 2
// baseline (1887.782 us; speedup 1.0000x reference)
//
#include <hip/hip_runtime.h>
#include <hip/hip_bf16.h>
#include <math.h>

// Problem constants (reference: B,T,D=64, E=HA=HB=128, OUT=1, short=2)
#define B_ 64
#define T_ 64
#define D_ 64
#define E_ 128
#define GG 768
#define PMIN 3        // short+1
#define NPOUT 60      // T-2-short
#define NCHUNK 4      // batch chunks of 16 per prefix

typedef __hip_bfloat16 bf16;

// ---- canonical fp32 input copies (element offsets within OFF_IN) ----
#define CI_X      0
#define CI_WEMB   262144
#define CI_BEMB   270336
#define CI_WIA    270464
#define CI_WHA    319616
#define CI_BIA    368768
#define CI_BHA    369152
#define CI_WIB    369536
#define CI_WHB    418688
#define CI_BIB    467840
#define CI_BHB    468224
#define CI_WA     468608
#define CI_BA     468736
#define CI_WB     468737
#define CI_BB     485121
#define CI_WO     485249
#define CI_BO     485377
#define CI_TOTAL  485378

// ---- workspace layout (fp32 elements) ----
#define OFF_EMB 0
#define OFF_GI  (OFF_EMB + T_*B_*E_)            // [t][b][768] gi (both cells, bias included)
#define OFF_WA  (OFF_GI  + T_*B_*GG)            // WA2  [k][384]
#define OFF_WBU (OFF_WA  + 128*384)             // WB2  [k][512]
#define OFF_WIC (OFF_WBU + 128*512)             // WicT [e][768]
#define OFF_WM  (OFF_WIC + 128*768)             // Wm   [e][64] = Wo[e]*W_emb[e][d]
#define OFF_IN  (OFF_WM  + 128*64)              // canonical fp32 inputs
#define OFF_FLAG_I (OFF_IN + CI_TOTAL)          // int flag: 1 = fp32 inputs, 0 = bf16

__device__ __forceinline__ float b2f(bf16 v) { return __bfloat162float(v); }
__device__ __forceinline__ float sigmoidf_(float v) { return 1.f / (1.f + __expf(-v)); }
__device__ __forceinline__ float tanhf_(float v) {
    float e = __expf(-2.f * fabsf(v));
    float t = (1.f - e) / (1.f + e);
    return copysignf(t, v);
}

// ---------------- dtype detection ----------------
// Interpret first 4096 halfwords of x as bf16. Genuine bf16 N(0,1): no value
// with exponent >= 140 (|v|>8192 or inf/nan). fp32 data read as bf16: ~45% of
// low halfwords are "bad". flag=1 -> inputs are fp32.
__global__ void detect_dtype(const unsigned short* xr, int* flag)
{
    int tid = threadIdx.x;
    int bad = 0;
    for (int i = tid; i < 4096; i += 256) {
        int ex = (xr[i] >> 7) & 0xFF;
        if (ex >= 140) bad++;
    }
    __shared__ int s[256];
    s[tid] = bad;
    __syncthreads();
    for (int st = 128; st > 0; st >>= 1) {
        if (tid < st) s[tid] += s[tid + st];
        __syncthreads();
    }
    if (tid == 0) *flag = (s[0] > 4) ? 1 : 0;
}

// ---------------- canonicalize all float inputs to fp32 in ws ----------------
__global__ void convert_inputs(const void* p0, const void* p1, const void* p2,
                               const void* p3, const void* p4, const void* p5,
                               const void* p6, const void* p7, const void* p8,
                               const void* p9, const void* p10, const void* p11,
                               const void* p12, const void* p13, const void* p14,
                               const void* p15, const void* p16,
                               float* ws, const int* flagp)
{
    const int flag = *flagp;
    int id = blockIdx.x * 256 + threadIdx.x;
    if (id >= CI_TOTAL) return;
    const int starts[18] = {CI_X, CI_WEMB, CI_BEMB, CI_WIA, CI_WHA, CI_BIA,
                            CI_BHA, CI_WIB, CI_WHB, CI_BIB, CI_BHB, CI_WA,
                            CI_BA, CI_WB, CI_BB, CI_WO, CI_BO, CI_TOTAL};
    const void* ptrs[17] = {p0,p1,p2,p3,p4,p5,p6,p7,p8,p9,p10,p11,p12,p13,p14,p15,p16};
    int k = 0;
    while (id >= starts[k + 1]) k++;
    int li = id - starts[k];
    float v = flag ? ((const float*)ptrs[k])[li]
                   : b2f(((const bf16*)ptrs[k])[li]);
    ws[OFF_IN + id] = v;
}

// ---------------- prep kernels (all read canonical fp32) ----------------

__global__ void prep_weights(float* ws)
{
    const float* cin = ws + OFF_IN;
    int id = blockIdx.x * 256 + threadIdx.x;
    if (id < 49152) {                                   // WA2 [k][384]
        int k = id / 384, c = id % 384;
        int lane = c / 6, i = c % 6;
        int kk = i / 3, t = i % 3;
        int row = t * 128 + lane + 64 * kk;
        ws[OFF_WA + id] = cin[CI_WHA + row * 128 + k];
    } else if (id < 49152 + 65536) {                    // WB2 [k][512]
        int id2 = id - 49152;
        int k = id2 / 512, c = id2 % 512;
        int lane = c / 8, i = c % 8;
        float v;
        if (i < 6) {
            int kk = i / 3, t = i % 3;
            int row = t * 128 + lane + 64 * kk;
            v = cin[CI_WHB + row * 128 + k];
        } else {
            int e = lane + 64 * (i - 6);
            v = cin[CI_WB + e * 128 + k];
        }
        ws[OFF_WBU + id2] = v;
    } else if (id < 49152 + 65536 + 98304) {            // WicT [e][768]
        int id2 = id - 49152 - 65536;
        int e = id2 / 768, g = id2 % 768;
        float v = (g < 384) ? cin[CI_WIA + g * 128 + e]
                            : cin[CI_WIB + (g - 384) * 128 + e];
        ws[OFF_WIC + id2] = v;
    } else if (id < 221184) {                           // Wm [e][64]
        int id2 = id - 49152 - 65536 - 98304;
        int e = id2 / 64;
        ws[OFF_WM + id2] = cin[CI_WO + e] * cin[CI_WEMB + id2];
    }
}

__global__ void prep_emb(float* ws)
{
    const float* cin = ws + OFF_IN;
    int id = blockIdx.x * 256 + threadIdx.x;   // T*B*E = 524288
    int e = id & 127;
    int tb = id >> 7;
    int b = tb & 63, t = tb >> 6;
    const float* xp = cin + CI_X + (b * T_ + t) * D_;
    const float* wp = cin + CI_WEMB + e * D_;
    float acc = cin[CI_BEMB + e];
    #pragma unroll
    for (int d = 0; d < 64; d += 4) {
        float4 xv = *(const float4*)(xp + d);
        float4 wv = *(const float4*)(wp + d);
        acc += xv.x * wv.x + xv.y * wv.y + xv.z * wv.z + xv.w * wv.w;
    }
    ws[OFF_EMB + id] = acc;
}

__global__ void prep_gi(float* ws)
{
    const float* cin = ws + OFF_IN;
    int t = blockIdx.x >> 2;
    int b0 = (blockIdx.x & 3) * 16;
    int tid = threadIdx.x;
    __shared__ __align__(16) float sembT[128][20];
    #pragma unroll
    for (int q = 0; q < 8; q++) {
        int idx = tid + q * 256;
        int r = idx >> 7, e = idx & 127;
        sembT[e][r] = ws[OFF_EMB + (size_t)((t * 64 + b0 + r) * 128) + e];
    }
    __syncthreads();
    float acc[3][16];
    #pragma unroll
    for (int g3 = 0; g3 < 3; g3++)
        #pragma unroll
        for (int r = 0; r < 16; r++) acc[g3][r] = 0.f;
    const float* wic = ws + OFF_WIC;
    for (int e = 0; e < 128; e++) {
        float4 h0 = *(const float4*)&sembT[e][0];
        float4 h1 = *(const float4*)&sembT[e][4];
        float4 h2 = *(const float4*)&sembT[e][8];
        float4 h3 = *(const float4*)&sembT[e][12];
        float hv[16] = {h0.x,h0.y,h0.z,h0.w, h1.x,h1.y,h1.z,h1.w,
                        h2.x,h2.y,h2.z,h2.w, h3.x,h3.y,h3.z,h3.w};
        float w0 = wic[e * 768 + tid];
        float w1 = wic[e * 768 + tid + 256];
        float w2 = wic[e * 768 + tid + 512];
        #pragma unroll
        for (int r = 0; r < 16; r++) {
            acc[0][r] += hv[r] * w0;
            acc[1][r] += hv[r] * w1;
            acc[2][r] += hv[r] * w2;
        }
    }
    #pragma unroll
    for (int g3 = 0; g3 < 3; g3++) {
        int g = tid + g3 * 256;
        float bias = (g < 384) ? cin[CI_BIA + g] : cin[CI_BIB + g - 384];
        #pragma unroll
        for (int r = 0; r < 16; r++)
            ws[OFF_GI + (size_t)(t * 64 + b0 + r) * 768 + g] = acc[g3][r] + bias;
    }
}

// ---------------- fused chain kernel ----------------
// One WG per (prefix p, batch chunk of 16). Runs the whole reversed-prefix
// double-GRU chain with online-softmax attention accumulation; h lives in LDS.

__launch_bounds__(256, 1)
__global__ void chain_kernel(const float* ws, void* outv, const int* flagp)
{
    const float* cin = ws + OFF_IN;
    const int flag = *flagp;
    const int p = PMIN + (int)blockIdx.x / NCHUNK;
    const int chunk = (int)blockIdx.x % NCHUNK;
    const int tid = threadIdx.x;
    const int lane = tid & 63;
    const int wid = tid >> 6;
    const int rg = wid >> 1;   // row-group: rows rg*8..rg*8+7
    const int gg = wid & 1;    // 0: cell-a gates, 1: cell-b gates + betapre

    __shared__ __align__(16) float hTa[128][20];
    __shared__ __align__(16) float hTb[128][20];
    __shared__ __align__(16) float betT[128][20];
    __shared__ float cAcc[16][128];
    __shared__ float gAcc[16][64];
    __shared__ float sm[16], sl[16], spa[16];
    __shared__ float sWa[128], sWo[128], sbb[128];
    __shared__ float sbh[768];

    for (int idx = tid; idx < 128 * 20; idx += 256) {
        (&hTa[0][0])[idx] = 0.f;
        (&hTb[0][0])[idx] = 0.f;
    }
    for (int idx = tid; idx < 16 * 128; idx += 256) (&cAcc[0][0])[idx] = 0.f;
    for (int idx = tid; idx < 16 * 64; idx += 256) (&gAcc[0][0])[idx] = 0.f;
    if (tid < 16) { sm[tid] = -INFINITY; sl[tid] = 0.f; spa[tid] = 0.f; }
    if (tid < 128) {
        sWa[tid] = cin[CI_WA + tid];
        sWo[tid] = cin[CI_WO + tid];
        sbb[tid] = cin[CI_BB + tid];
    }
    for (int idx = tid; idx < 768; idx += 256)
        sbh[idx] = (idx < 384) ? cin[CI_BHA + idx] : cin[CI_BHB + idx - 384];
    __syncthreads();

    const float baf = cin[CI_BA];
    const float bof = cin[CI_BO];
    const int cellbase = gg ? 384 : 0;

    // iteration it: K-loop computes gh_it (from h_it) AND betapre(h_it) in one
    // pass; GRU update -> h_{it+1}; doAcc consumes state h_it (scan step it-1).
    for (int it = 0; it <= p + 1; it++) {
        const int j = p - it;        // GRU input timestep
        const int jp = j + 1;        // accumulation timestep (scan step it-1)
        const bool doAcc = (it > 0);
        const bool doGru = (it <= p);

        float acc[8][8];
        #pragma unroll
        for (int i = 0; i < 8; i++)
            #pragma unroll
            for (int r = 0; r < 8; r++) acc[i][r] = 0.f;

        if (gg == 0) {               // cell-a gates: 6 cols/lane (2 kh x r,z,n)
            const float* wp = ws + OFF_WA + lane * 6;
            #pragma unroll 2
            for (int k = 0; k < 128; k++) {
                float4 h0 = *(const float4*)&hTa[k][rg * 8];
                float4 h1 = *(const float4*)&hTa[k][rg * 8 + 4];
                float2 w01 = *(const float2*)(wp + k * 384);
                float2 w23 = *(const float2*)(wp + k * 384 + 2);
                float2 w45 = *(const float2*)(wp + k * 384 + 4);
                float hv[8] = {h0.x,h0.y,h0.z,h0.w, h1.x,h1.y,h1.z,h1.w};
                float wvv[6] = {w01.x,w01.y, w23.x,w23.y, w45.x,w45.y};
                #pragma unroll
                for (int i = 0; i < 6; i++)
                    #pragma unroll
                    for (int r = 0; r < 8; r++)
                        acc[i][r] += wvv[i] * hv[r];
            }
        } else {                     // cell-b gates (6) + betapre (2) per lane
            const float* wp = ws + OFF_WBU + lane * 8;
            #pragma unroll 2
            for (int k = 0; k < 128; k++) {
                float4 h0 = *(const float4*)&hTb[k][rg * 8];
                float4 h1 = *(const float4*)&hTb[k][rg * 8 + 4];
                float4 wA = *(const float4*)(wp + k * 512);
                float4 wB = *(const float4*)(wp + k * 512 + 4);
                float hv[8] = {h0.x,h0.y,h0.z,h0.w, h1.x,h1.y,h1.z,h1.w};
                float wvv[8] = {wA.x,wA.y,wA.z,wA.w, wB.x,wB.y,wB.z,wB.w};
                #pragma unroll
                for (int i = 0; i < 8; i++)
                    #pragma unroll
                    for (int r = 0; r < 8; r++)
                        acc[i][r] += wvv[i] * hv[r];
            }
        }

        // GRU nonlinearity fully in-register (lane owns r,z,n of its kh's)
        float hnew[16];
        if (doGru) {
            #pragma unroll
            for (int kk = 0; kk < 2; kk++) {
                const int kh = lane + 64 * kk;
                #pragma unroll
                for (int r = 0; r < 8; r++) {
                    const int row = rg * 8 + r;
                    const int bglob = chunk * 16 + row;
                    const float* gip = ws + OFF_GI + (size_t)(j * B_ + bglob) * 768 + cellbase + kh;
                    float gir = gip[0], giz = gip[128], gin = gip[256];
                    float ghr = acc[3 * kk + 0][r] + sbh[cellbase + kh];
                    float ghz = acc[3 * kk + 1][r] + sbh[cellbase + 128 + kh];
                    float ghn = acc[3 * kk + 2][r] + sbh[cellbase + 256 + kh];
                    float hold = gg ? hTb[kh][row] : hTa[kh][row];
                    float rr = sigmoidf_(gir + ghr);
                    float zz = sigmoidf_(giz + ghz);
                    float nn = tanhf_(gin + rr * ghn);
                    hnew[kk * 8 + r] = (1.f - zz) * nn + zz * hold;
                }
            }
        }

        __syncthreads();   // BAR1: all reads of h_it done

        if (doGru) {
            #pragma unroll
            for (int kk = 0; kk < 2; kk++) {
                const int kh = lane + 64 * kk;
                #pragma unroll
                for (int r = 0; r < 8; r++) {
                    if (gg) hTb[kh][rg * 8 + r] = hnew[kk * 8 + r];
                    else    hTa[kh][rg * 8 + r] = hnew[kk * 8 + r];
                }
            }
        }
        if (gg == 1) {      // raw betapre(h_it) for scan step it-1
            #pragma unroll
            for (int i = 6; i < 8; i++) {
                const int e = lane + 64 * (i - 6);
                #pragma unroll
                for (int r = 0; r < 8; r++)
                    betT[e][rg * 8 + r] = acc[i][r];
            }
        }
        __syncthreads();   // BAR2

        if (doAcc) {        // tanh(beta) + online-softmax update of cAcc
            #pragma unroll
            for (int q2 = 0; q2 < 8; q2++) {
                const int idx = tid + 256 * q2;
                const int r = idx >> 7, e = idx & 127;
                float m_old = sm[r], pav = spa[r];
                float m_new = fmaxf(m_old, pav);
                float sc = __expf(m_old - m_new);
                float wexp = __expf(pav - m_new);
                float bet = tanhf_(0.5f * betT[e][r] + sbb[e]);
                betT[e][r] = bet;
                float embv = ws[OFF_EMB + (size_t)(jp * B_ + chunk * 16 + r) * 128 + e];
                cAcc[r][e] = cAcc[r][e] * sc + wexp * bet * embv;
            }
        }
        __syncthreads();   // BAR3

        if (doAcc) {        // e_chain = beta @ (Wo*W_emb), update gAcc
            const int d = lane;
            float ec[4] = {0.f, 0.f, 0.f, 0.f};
            #pragma unroll 4
            for (int e = 0; e < 128; e++) {
                float4 bv = *(const float4*)&betT[e][wid * 4];
                float wm = ws[OFF_WM + e * 64 + d];
                ec[0] += bv.x * wm; ec[1] += bv.y * wm;
                ec[2] += bv.z * wm; ec[3] += bv.w * wm;
            }
            #pragma unroll
            for (int q2 = 0; q2 < 4; q2++) {
                const int r = wid * 4 + q2;
                float m_old = sm[r], pav = spa[r];
                float m_new = fmaxf(m_old, pav);
                float sc = __expf(m_old - m_new);
                float wexp = __expf(pav - m_new);
                const int bglob = chunk * 16 + r;
                float xv = cin[CI_X + (size_t)(bglob * T_ + jp) * 64 + d];
                gAcc[r][d] = gAcc[r][d] * sc + wexp * ec[q2] * xv;
            }
        }
        __syncthreads();   // BAR4

        if (doAcc && tid < 16) {   // softmax running max/denominator
            const int r = tid;
            float m_old = sm[r], pav = spa[r];
            float m_new = fmaxf(m_old, pav);
            float sc = __expf(m_old - m_new);
            sl[r] = sl[r] * sc + __expf(pav - m_new);
            sm[r] = m_new;
        }
        __syncthreads();   // BAR5

        if (doGru) {        // preA(h_{it+1}) for next iteration's doAcc
            const int r = tid >> 4, ks = tid & 15;
            float partial = 0.f;
            #pragma unroll
            for (int t2 = 0; t2 < 8; t2++) {
                const int k = ks + t2 * 16;
                partial += hTa[k][r] * sWa[k];
            }
            partial += __shfl_xor(partial, 1);
            partial += __shfl_xor(partial, 2);
            partial += __shfl_xor(partial, 4);
            partial += __shfl_xor(partial, 8);
            if (ks == 0) spa[r] = 0.5f * partial + baf;
        }
        __syncthreads();   // BAR6
    }

    // epilogue: pred = (c/l)@Wo + bo ; weight = g/l/(p+1)
    {
        const int r = tid >> 4, ks = tid & 15;
        float partial = 0.f;
        #pragma unroll
        for (int t2 = 0; t2 < 8; t2++) {
            const int e = ks + t2 * 16;
            partial += cAcc[r][e] * sWo[e];
        }
        partial += __shfl_xor(partial, 1);
        partial += __shfl_xor(partial, 2);
        partial += __shfl_xor(partial, 4);
        partial += __shfl_xor(partial, 8);
        if (ks == 0) {
            const int bglob = chunk * 16 + r;
            float pred = partial / sl[r] + bof;
            const size_t oi = (size_t)bglob * NPOUT + (p - PMIN);
            if (flag) ((float*)outv)[oi] = pred;
            else      ((bf16*)outv)[oi] = __float2bfloat16(pred);
        }
    }
    {
        const int d = lane;
        const float inv_t = 1.f / (float)(p + 1);
        #pragma unroll
        for (int q2 = 0; q2 < 4; q2++) {
            const int r = wid * 4 + q2;
            const int bglob = chunk * 16 + r;
            float gv = gAcc[r][d] / sl[r] * inv_t;
            const size_t oi = (size_t)B_ * NPOUT + (size_t)(bglob * NPOUT + (p - PMIN)) * 64 + d;
            if (flag) ((float*)outv)[oi] = gv;
            else      ((bf16*)outv)[oi] = __float2bfloat16(gv);
        }
    }
}

// ---------------- launch ----------------

extern "C" void kernel_launch(void* const* d_in, const int* in_sizes, int n_in,
                              void* d_out, int out_size, void* d_ws, size_t ws_size,
                              hipStream_t stream)
{
    float* ws = (float*)d_ws;
    int* flagp = (int*)(ws + OFF_FLAG_I);

    hipLaunchKernelGGL(detect_dtype, dim3(1), dim3(256), 0, stream,
                       (const unsigned short*)d_in[0], flagp);
    hipLaunchKernelGGL(convert_inputs, dim3((CI_TOTAL + 255) / 256), dim3(256), 0, stream,
                       d_in[0], d_in[1], d_in[2], d_in[3], d_in[4], d_in[5],
                       d_in[6], d_in[7], d_in[8], d_in[9], d_in[10], d_in[11],
                       d_in[12], d_in[13], d_in[14], d_in[15], d_in[16],
                       ws, flagp);
    hipLaunchKernelGGL(prep_weights, dim3(864), dim3(256), 0, stream, ws);
    hipLaunchKernelGGL(prep_emb, dim3(2048), dim3(256), 0, stream, ws);
    hipLaunchKernelGGL(prep_gi, dim3(256), dim3(256), 0, stream, ws);
    hipLaunchKernelGGL(chain_kernel, dim3(60 * NCHUNK), dim3(256), 0, stream,
                       ws, d_out, flagp);
}

// Round 3
// 690.228 us; speedup vs baseline: 2.7350x; 2.7350x over previous
//
#include <hip/hip_runtime.h>
#include <hip/hip_bf16.h>
#include <math.h>

// Problem constants (reference: B,T,D=64, E=HA=HB=128, OUT=1, short=2)
#define B_ 64
#define T_ 64
#define D_ 64
#define E_ 128
#define PMIN 3        // short+1
#define NPOUT 60      // T-2-short
#define NCHUNK 2      // batch chunks of 32 per prefix

typedef __hip_bfloat16 bf16;
typedef __attribute__((ext_vector_type(8))) short s16x8;
typedef __attribute__((ext_vector_type(4))) float f32x4;

// ---- canonical fp32 input copies (element offsets within OFF_IN) ----
#define CI_X      0
#define CI_WEMB   262144
#define CI_BEMB   270336
#define CI_WIA    270464
#define CI_WHA    319616
#define CI_BIA    368768
#define CI_BHA    369152
#define CI_WIB    369536
#define CI_WHB    418688
#define CI_BIB    467840
#define CI_BHB    468224
#define CI_WA     468608
#define CI_BA     468736
#define CI_WB     468737
#define CI_BB     485121
#define CI_WO     485249
#define CI_BO     485377
#define CI_TOTAL  485378

// ---- workspace layout (fp32 element offsets) ----
#define OFF_EMB   0                      // [t][b][128] fp32
#define OFF_GI    524288                 // [t][b][768] fp32 (bi folded)
#define OFF_WIC   3670016                // WicT [e][768] fp32
#define OFF_XT    3768320                // xt [t][d][b] fp32
#define OFF_IN    4030464                // canonical fp32 inputs
#define OFF_GIPK  4515844                // bf16 [t][chunk][w][lane][48]  (1572864 floats)
#define OFF_WPK   6088708                // bf16 [w][nt6][kt][lane][8]    (49152 floats)
#define OFF_BPPK  6137860                // bf16 [w8][kt][lane][8]        (8192 floats)
#define OFF_WMPK  6146052                // bf16 [nt4][kt][lane][8]       (4096 floats)
#define OFF_FLAG  6150148

__device__ __forceinline__ float bf2f(unsigned short u) {
    union { float f; unsigned u32; } x; x.u32 = ((unsigned)u) << 16; return x.f;
}
__device__ __forceinline__ unsigned short f2bf(float f) {
    union { float f; unsigned u; } x; x.f = f;
    unsigned r = x.u + 0x7FFFu + ((x.u >> 16) & 1u);
    return (unsigned short)(r >> 16);
}
__device__ __forceinline__ float sigmoidf_(float v) { return 1.f / (1.f + __expf(-v)); }
__device__ __forceinline__ float tanhf_(float v) {
    float e = __expf(-2.f * fabsf(v));
    float t = (1.f - e) / (1.f + e);
    return copysignf(t, v);
}

// ---------------- dtype detection ----------------
__global__ void detect_dtype(const unsigned short* xr, int* flag)
{
    int tid = threadIdx.x;
    int bad = 0;
    for (int i = tid; i < 4096; i += 256) {
        int ex = (xr[i] >> 7) & 0xFF;
        if (ex >= 140) bad++;
    }
    __shared__ int s[256];
    s[tid] = bad;
    __syncthreads();
    for (int st = 128; st > 0; st >>= 1) {
        if (tid < st) s[tid] += s[tid + st];
        __syncthreads();
    }
    if (tid == 0) *flag = (s[0] > 4) ? 1 : 0;
}

// ---------------- canonicalize inputs to fp32 ----------------
__global__ void convert_inputs(const void* p0, const void* p1, const void* p2,
                               const void* p3, const void* p4, const void* p5,
                               const void* p6, const void* p7, const void* p8,
                               const void* p9, const void* p10, const void* p11,
                               const void* p12, const void* p13, const void* p14,
                               const void* p15, const void* p16,
                               float* ws, const int* flagp)
{
    const int flag = *flagp;
    int id = blockIdx.x * 256 + threadIdx.x;
    if (id >= CI_TOTAL) return;
    const int starts[18] = {CI_X, CI_WEMB, CI_BEMB, CI_WIA, CI_WHA, CI_BIA,
                            CI_BHA, CI_WIB, CI_WHB, CI_BIB, CI_BHB, CI_WA,
                            CI_BA, CI_WB, CI_BB, CI_WO, CI_BO, CI_TOTAL};
    const void* ptrs[17] = {p0,p1,p2,p3,p4,p5,p6,p7,p8,p9,p10,p11,p12,p13,p14,p15,p16};
    int k = 0;
    while (id >= starts[k + 1]) k++;
    int li = id - starts[k];
    float v = flag ? ((const float*)ptrs[k])[li]
                   : bf2f(((const unsigned short*)ptrs[k])[li]);
    ws[OFF_IN + id] = v;
}

// ---------------- prep: WicT [e][768] ----------------
__global__ void prep_wic(float* ws)
{
    const float* cin = ws + OFF_IN;
    int id = blockIdx.x * 256 + threadIdx.x;   // 98304
    int e = id / 768, g = id % 768;
    float v = (g < 384) ? cin[CI_WIA + g * 128 + e]
                        : cin[CI_WIB + (g - 384) * 128 + e];
    ws[OFF_WIC + id] = v;
}

// ---------------- prep: emb [t][b][128] ----------------
__global__ void prep_emb(float* ws)
{
    const float* cin = ws + OFF_IN;
    int id = blockIdx.x * 256 + threadIdx.x;   // 524288
    int e = id & 127;
    int tb = id >> 7;
    int b = tb & 63, t = tb >> 6;
    const float* xp = cin + CI_X + (b * T_ + t) * D_;
    const float* wp = cin + CI_WEMB + e * D_;
    float acc = cin[CI_BEMB + e];
    #pragma unroll
    for (int d = 0; d < 64; d += 4) {
        f32x4 xv = *(const f32x4*)(xp + d);
        f32x4 wv = *(const f32x4*)(wp + d);
        acc += xv[0]*wv[0] + xv[1]*wv[1] + xv[2]*wv[2] + xv[3]*wv[3];
    }
    ws[OFF_EMB + id] = acc;
}

// ---------------- prep: xt [t][d][b] ----------------
__global__ void prep_xt(float* ws)
{
    const float* cin = ws + OFF_IN;
    int id = blockIdx.x * 256 + threadIdx.x;   // 262144
    int b = id & 63, d = (id >> 6) & 63, t = id >> 12;
    ws[OFF_XT + id] = cin[CI_X + (b * 64 + t) * 64 + d];
}

// ---------------- prep: gi [t][b][768] fp32 (bi folded) ----------------
__global__ void prep_gi(float* ws)
{
    const float* cin = ws + OFF_IN;
    int t = blockIdx.x >> 2;
    int b0 = (blockIdx.x & 3) * 16;
    int tid = threadIdx.x;
    __shared__ __align__(16) float sembT[128][20];
    #pragma unroll
    for (int q = 0; q < 8; q++) {
        int idx = tid + q * 256;
        int r = idx >> 7, e = idx & 127;
        sembT[e][r] = ws[OFF_EMB + (size_t)((t * 64 + b0 + r) * 128) + e];
    }
    __syncthreads();
    float acc[3][16];
    #pragma unroll
    for (int g3 = 0; g3 < 3; g3++)
        #pragma unroll
        for (int r = 0; r < 16; r++) acc[g3][r] = 0.f;
    const float* wic = ws + OFF_WIC;
    for (int e = 0; e < 128; e++) {
        f32x4 h0 = *(const f32x4*)&sembT[e][0];
        f32x4 h1 = *(const f32x4*)&sembT[e][4];
        f32x4 h2 = *(const f32x4*)&sembT[e][8];
        f32x4 h3 = *(const f32x4*)&sembT[e][12];
        float hv[16] = {h0[0],h0[1],h0[2],h0[3], h1[0],h1[1],h1[2],h1[3],
                        h2[0],h2[1],h2[2],h2[3], h3[0],h3[1],h3[2],h3[3]};
        float w0 = wic[e * 768 + tid];
        float w1 = wic[e * 768 + tid + 256];
        float w2 = wic[e * 768 + tid + 512];
        #pragma unroll
        for (int r = 0; r < 16; r++) {
            acc[0][r] += hv[r] * w0;
            acc[1][r] += hv[r] * w1;
            acc[2][r] += hv[r] * w2;
        }
    }
    #pragma unroll
    for (int g3 = 0; g3 < 3; g3++) {
        int g = tid + g3 * 256;
        float bias = (g < 384) ? cin[CI_BIA + g] : cin[CI_BIB + g - 384];
        #pragma unroll
        for (int r = 0; r < 16; r++)
            ws[OFF_GI + (size_t)(t * 64 + b0 + r) * 768 + g] = acc[g3][r] + bias;
    }
}

// ---------------- prep: pack gi into per-lane bf16 (bh_r, bh_z folded) ----------------
__global__ void prep_gipack(float* ws)
{
    const float* cin = ws + OFF_IN;
    unsigned short* gipk = (unsigned short*)(ws + OFF_GIPK);
    int id = blockIdx.x * 256 + threadIdx.x;     // 3145728
    int slot = id % 48;
    int lane = (id / 48) & 63;
    int w = (id / 3072) & 7;
    int chunk = (id / 24576) & 1;
    int t = id / 49152;
    int reg = slot & 3, mt = (slot >> 2) & 1, gate = (slot >> 3) % 3, tt = slot / 24;
    int cell = w >> 2, wv = w & 3;
    int g = cell * 384 + gate * 128 + wv * 32 + tt * 16 + (lane & 15);
    int b = chunk * 32 + mt * 16 + (lane >> 4) * 4 + reg;
    float v = ws[OFF_GI + (size_t)(t * 64 + b) * 768 + g];
    if (gate < 2)
        v += cin[(cell ? CI_BHB : CI_BHA) + gate * 128 + wv * 32 + tt * 16 + (lane & 15)];
    gipk[id] = f2bf(v);
}

// ---------------- prep: pack weights into MFMA B-fragment order ----------------
__global__ void prep_pack(float* ws)
{
    const float* cin = ws + OFF_IN;
    int id = blockIdx.x * 256 + threadIdx.x;     // 122880
    if (id < 98304) {                            // gh weights: [w][nt][kt][lane][8]
        unsigned short* wpk = (unsigned short*)(ws + OFF_WPK);
        int w = id / 12288, r1 = id % 12288;
        int nt = r1 / 2048, r2 = r1 % 2048;
        int kt = r2 / 512, r3 = r2 % 512;
        int lane = r3 >> 3, j = r3 & 7;
        int cell = w >> 2, wv = w & 3;
        int gate = nt >> 1, tt = nt & 1;
        int g = gate * 128 + wv * 32 + tt * 16 + (lane & 15);
        int k = kt * 32 + (lane >> 4) * 8 + j;
        wpk[id] = f2bf(cin[(cell ? CI_WHB : CI_WHA) + g * 128 + k]);
    } else if (id < 98304 + 16384) {             // Wb: [w][kt][lane][8]
        unsigned short* bpk = (unsigned short*)(ws + OFF_BPPK);
        int id2 = id - 98304;
        int w = id2 / 2048, r = id2 % 2048;
        int kt = r / 512, lane = (r % 512) >> 3, j = r & 7;
        int e = w * 16 + (lane & 15);
        int k = kt * 32 + (lane >> 4) * 8 + j;
        bpk[id2] = f2bf(cin[CI_WB + e * 128 + k]);
    } else {                                     // Wm: [nt][kt][lane][8]
        unsigned short* wmk = (unsigned short*)(ws + OFF_WMPK);
        int id3 = id - 98304 - 16384;
        int nt = id3 / 2048, r = id3 % 2048;
        int kt = r / 512, lane = (r % 512) >> 3, j = r & 7;
        int d = nt * 16 + (lane & 15);
        int e = kt * 32 + (lane >> 4) * 8 + j;
        wmk[id3] = f2bf(cin[CI_WO + e] * cin[CI_WEMB + e * 64 + d]);
    }
}

// ---------------- fused chain kernel (MFMA) ----------------
// 120 WGs: (prefix p, batch half of 32). 512 threads = 8 waves.
// Waves 0-3: cell-a gates (kh = wv*32..+32) + betapre e in [w*16,w*16+16).
// Waves 4-7: cell-b gates + betapre e in [w*16,w*16+16).
// Wh B-fragments live in 96 VGPRs per wave for the whole kernel.

__launch_bounds__(512)
__global__ void chain_kernel(const float* ws, void* outv, const int* flagp)
{
    const int p = PMIN + (int)blockIdx.x / NCHUNK;
    const int chunk = (int)blockIdx.x % NCHUNK;
    const int tid = threadIdx.x;
    const int lane = tid & 63;
    const int w = tid >> 6;
    const int cell = w >> 2;
    const int wv = w & 3;
    const int l15 = lane & 15;
    const int quad = lane >> 4;

    __shared__ __align__(16) short hbf[2][2][32][136];   // [cell][buf][row][kh]
    __shared__ __align__(16) short betbf[32][136];
    __shared__ __align__(16) short sBp[8][4][64][8];
    __shared__ __align__(16) short sWm[4][4][64][8];
    __shared__ __align__(16) float cAcc[32][128];
    __shared__ float spaPart[4][32];
    __shared__ float scArr[32], weArr[32], slFin[32];

    const float* cin = ws + OFF_IN;
    const unsigned short* gipk = (const unsigned short*)(ws + OFF_GIPK);
    const unsigned short* wpk  = (const unsigned short*)(ws + OFF_WPK);

    // stage Wb / Wm fragment packs into LDS; zero h and cAcc
    {
        const int* s1 = (const int*)(ws + OFF_BPPK);
        int* d1 = (int*)&sBp[0][0][0][0];
        for (int i = tid; i < 8192; i += 512) d1[i] = s1[i];
        const int* s2 = (const int*)(ws + OFF_WMPK);
        int* d2 = (int*)&sWm[0][0][0][0];
        for (int i = tid; i < 4096; i += 512) d2[i] = s2[i];
        int* hz = (int*)&hbf[0][0][0][0];
        for (int i = tid; i < 8704; i += 512) hz[i] = 0;
        float* cz = &cAcc[0][0];
        for (int i = tid; i < 4096; i += 512) cz[i] = 0.f;
    }

    // persistent weight registers: 6 gate n-tiles x 4 k-tiles
    s16x8 wB[6][4];
    #pragma unroll
    for (int nt = 0; nt < 6; nt++)
        #pragma unroll
        for (int kt = 0; kt < 4; kt++)
            wB[nt][kt] = *(const s16x8*)(wpk + (((w * 6 + nt) * 4 + kt) * 64 + lane) * 8);

    // per-lane constants
    const float bhn0 = cin[(cell ? CI_BHB : CI_BHA) + 256 + wv * 32 + l15];
    const float bhn1 = cin[(cell ? CI_BHB : CI_BHA) + 256 + wv * 32 + 16 + l15];
    const float wa0  = cin[CI_WA + wv * 32 + l15];
    const float wa1  = cin[CI_WA + wv * 32 + 16 + l15];
    const float bbE  = cin[CI_BB + w * 16 + l15];
    const float baf  = cin[CI_BA];
    const float bof  = cin[CI_BO];
    const int flag = *flagp;

    float h_old[16];                     // [tt][mt][reg] fp32 state
    #pragma unroll
    for (int i = 0; i < 16; i++) h_old[i] = 0.f;
    float gAccR[8];                      // waves 0-3: [mt][reg], d = w*16+l15
    #pragma unroll
    for (int i = 0; i < 8; i++) gAccR[i] = 0.f;
    float sm_reg = -INFINITY, sl_reg = 0.f;   // wave 7 lanes 0-31

    int cur = 0;
    __syncthreads();

    for (int it = 0; it <= p + 1; it++) {
        const int j = p - it;
        const int jp = j + 1;
        const bool doGru = (j >= 0);
        const bool doAcc = (it > 0);

        // gi prefetch (per-lane packed bf16, biases folded)
        s16x8 giv[6];
        if (doGru) {
            const unsigned short* gp =
                gipk + ((((size_t)j * 2 + chunk) * 8 + w) * 64 + lane) * 48;
            #pragma unroll
            for (int i = 0; i < 6; i++) giv[i] = *(const s16x8*)(gp + i * 8);
        }

        // ---- Phase A: MFMA gh + betapre from h_it ----
        f32x4 C[7][2];
        #pragma unroll
        for (int nt = 0; nt < 7; nt++)
            #pragma unroll
            for (int mt = 0; mt < 2; mt++)
                C[nt][mt] = (f32x4){0.f, 0.f, 0.f, 0.f};

        #pragma unroll
        for (int kt = 0; kt < 4; kt++) {
            s16x8 aOwn0 = *(const s16x8*)&hbf[cell][cur][l15][kt * 32 + quad * 8];
            s16x8 aOwn1 = *(const s16x8*)&hbf[cell][cur][16 + l15][kt * 32 + quad * 8];
            s16x8 aBp0, aBp1;
            if (cell == 0) {
                aBp0 = *(const s16x8*)&hbf[1][cur][l15][kt * 32 + quad * 8];
                aBp1 = *(const s16x8*)&hbf[1][cur][16 + l15][kt * 32 + quad * 8];
            } else { aBp0 = aOwn0; aBp1 = aOwn1; }
            #pragma unroll
            for (int nt = 0; nt < 6; nt++) {
                C[nt][0] = __builtin_amdgcn_mfma_f32_16x16x32_bf16(aOwn0, wB[nt][kt], C[nt][0], 0, 0, 0);
                C[nt][1] = __builtin_amdgcn_mfma_f32_16x16x32_bf16(aOwn1, wB[nt][kt], C[nt][1], 0, 0, 0);
            }
            s16x8 bbp = *(const s16x8*)&sBp[w][kt][lane][0];
            C[6][0] = __builtin_amdgcn_mfma_f32_16x16x32_bf16(aBp0, bbp, C[6][0], 0, 0, 0);
            C[6][1] = __builtin_amdgcn_mfma_f32_16x16x32_bf16(aBp1, bbp, C[6][1], 0, 0, 0);
        }

        // ---- Phase B ----
        // spa partials from OLD h (cell-a waves), before h update
        if (cell == 0) {
            #pragma unroll
            for (int mt = 0; mt < 2; mt++)
                #pragma unroll
                for (int reg = 0; reg < 4; reg++) {
                    float pv = h_old[mt * 4 + reg] * wa0 + h_old[8 + mt * 4 + reg] * wa1;
                    pv += __shfl_xor(pv, 1);
                    pv += __shfl_xor(pv, 2);
                    pv += __shfl_xor(pv, 4);
                    pv += __shfl_xor(pv, 8);
                    if (l15 == 0) spaPart[wv][mt * 16 + quad * 4 + reg] = pv;
                }
        }

        // GRU nonlinearity fully in-register; write h_{it+1} bf16 to hbf[nxt]
        if (doGru) {
            #pragma unroll
            for (int tt = 0; tt < 2; tt++)
                #pragma unroll
                for (int mt = 0; mt < 2; mt++)
                    #pragma unroll
                    for (int reg = 0; reg < 4; reg++) {
                        const int me = mt * 4 + reg;
                        float gir = bf2f((unsigned short)giv[tt * 3 + 0][me]);
                        float giz = bf2f((unsigned short)giv[tt * 3 + 1][me]);
                        float gin = bf2f((unsigned short)giv[tt * 3 + 2][me]);
                        float ghr = C[0 + tt][mt][reg];
                        float ghz = C[2 + tt][mt][reg];
                        float ghn = C[4 + tt][mt][reg] + (tt ? bhn1 : bhn0);
                        float ho  = h_old[tt * 8 + mt * 4 + reg];
                        float rr = sigmoidf_(gir + ghr);
                        float zz = sigmoidf_(giz + ghz);
                        float nn = tanhf_(gin + rr * ghn);
                        float hn2 = (1.f - zz) * nn + zz * ho;
                        h_old[tt * 8 + mt * 4 + reg] = hn2;
                        hbf[cell][cur ^ 1][mt * 16 + quad * 4 + reg][wv * 32 + tt * 16 + l15] =
                            (short)f2bf(hn2);
                    }
        }
        // beta = tanh(0.5*betapre + bb) -> betbf (A-layout source for e_chain)
        #pragma unroll
        for (int mt = 0; mt < 2; mt++)
            #pragma unroll
            for (int reg = 0; reg < 4; reg++) {
                float bv = tanhf_(0.5f * C[6][mt][reg] + bbE);
                betbf[mt * 16 + quad * 4 + reg][w * 16 + l15] = (short)f2bf(bv);
            }
        __syncthreads();   // BAR_mid: betbf, spaPart ready

        // ---- Phase B2: softmax scalars (wave 7, lanes 0-31; row = lane) ----
        if (w == 7 && lane < 32) {
            float pav = 0.5f * (spaPart[0][lane] + spaPart[1][lane] +
                                spaPart[2][lane] + spaPart[3][lane]) + baf;
            if (doAcc) {
                float mnew = fmaxf(sm_reg, pav);
                float sc = __expf(sm_reg - mnew);
                float we = __expf(pav - mnew);
                scArr[lane] = sc;
                weArr[lane] = we;
                sl_reg = sl_reg * sc + we;
                sm_reg = mnew;
            }
        }
        __syncthreads();   // BAR_mid2: scArr/weArr ready

        // ---- Phase C: attention accumulation (scan step s = it-1, h_it) ----
        if (doAcc) {
            if (w < 4) {
                // e_chain = beta @ Wm  (n-tile = w: d in [w*16, w*16+16))
                f32x4 ec0 = (f32x4){0.f, 0.f, 0.f, 0.f};
                f32x4 ec1 = (f32x4){0.f, 0.f, 0.f, 0.f};
                #pragma unroll
                for (int kt = 0; kt < 4; kt++) {
                    s16x8 a0 = *(const s16x8*)&betbf[l15][kt * 32 + quad * 8];
                    s16x8 a1 = *(const s16x8*)&betbf[16 + l15][kt * 32 + quad * 8];
                    s16x8 bw = *(const s16x8*)&sWm[w][kt][lane][0];
                    ec0 = __builtin_amdgcn_mfma_f32_16x16x32_bf16(a0, bw, ec0, 0, 0, 0);
                    ec1 = __builtin_amdgcn_mfma_f32_16x16x32_bf16(a1, bw, ec1, 0, 0, 0);
                }
                // gAcc += wexp * ec * x[jp]   (registers)
                #pragma unroll
                for (int mt = 0; mt < 2; mt++) {
                    const float* xp = ws + OFF_XT + ((size_t)jp * 64 + w * 16 + l15) * 64
                                      + chunk * 32 + mt * 16 + quad * 4;
                    f32x4 xv = *(const f32x4*)xp;
                    #pragma unroll
                    for (int reg = 0; reg < 4; reg++) {
                        int row = mt * 16 + quad * 4 + reg;
                        float sc = scArr[row], we = weArr[row];
                        float ecv = mt ? ec1[reg] : ec0[reg];
                        gAccR[mt * 4 + reg] = gAccR[mt * 4 + reg] * sc + we * ecv * xv[reg];
                    }
                }
            } else {
                // cAcc += wexp * beta * emb[jp]   (LDS, owner-exclusive)
                int q = tid - 256;
                int r = q >> 3, e0 = (q & 7) * 16;
                float sc = scArr[r], we = weArr[r];
                const float* ep = ws + OFF_EMB + ((size_t)jp * 64 + chunk * 32 + r) * 128 + e0;
                #pragma unroll
                for (int u = 0; u < 16; u += 4) {
                    f32x4 em = *(const f32x4*)(ep + u);
                    #pragma unroll
                    for (int v = 0; v < 4; v++) {
                        float bet = bf2f((unsigned short)betbf[r][e0 + u + v]);
                        cAcc[r][e0 + u + v] = cAcc[r][e0 + u + v] * sc + we * bet * em[v];
                    }
                }
            }
        }
        cur ^= 1;
        __syncthreads();   // BAR_end
    }

    // ---- epilogue ----
    if (w == 7 && lane < 32) slFin[lane] = sl_reg;
    __syncthreads();

    {   // pred = (c/l) . Wo + bo
        int r = tid >> 4, ks = tid & 15;
        float part = 0.f;
        #pragma unroll
        for (int t2 = 0; t2 < 8; t2++) {
            int e = ks + t2 * 16;
            part += cAcc[r][e] * cin[CI_WO + e];
        }
        part += __shfl_xor(part, 1);
        part += __shfl_xor(part, 2);
        part += __shfl_xor(part, 4);
        part += __shfl_xor(part, 8);
        if (ks == 0) {
            int bglob = chunk * 32 + r;
            float pr = part / slFin[r] + bof;
            size_t oi = (size_t)bglob * NPOUT + (p - PMIN);
            if (flag) ((float*)outv)[oi] = pr;
            else      ((bf16*)outv)[oi] = __float2bfloat16(pr);
        }
    }
    if (w < 4) {   // weight = g/l/(p+1)
        const float invt = 1.f / (float)(p + 1);
        #pragma unroll
        for (int mt = 0; mt < 2; mt++)
            #pragma unroll
            for (int reg = 0; reg < 4; reg++) {
                int row = mt * 16 + quad * 4 + reg;
                int bglob = chunk * 32 + row;
                float gv = gAccR[mt * 4 + reg] / slFin[row] * invt;
                size_t oi = (size_t)B_ * NPOUT
                          + ((size_t)bglob * NPOUT + (p - PMIN)) * 64 + w * 16 + l15;
                if (flag) ((float*)outv)[oi] = gv;
                else      ((bf16*)outv)[oi] = __float2bfloat16(gv);
            }
    }
}

// ---------------- launch ----------------
extern "C" void kernel_launch(void* const* d_in, const int* in_sizes, int n_in,
                              void* d_out, int out_size, void* d_ws, size_t ws_size,
                              hipStream_t stream)
{
    float* ws = (float*)d_ws;
    int* flagp = (int*)(ws + OFF_FLAG);

    hipLaunchKernelGGL(detect_dtype, dim3(1), dim3(256), 0, stream,
                       (const unsigned short*)d_in[0], flagp);
    hipLaunchKernelGGL(convert_inputs, dim3((CI_TOTAL + 255) / 256), dim3(256), 0, stream,
                       d_in[0], d_in[1], d_in[2], d_in[3], d_in[4], d_in[5],
                       d_in[6], d_in[7], d_in[8], d_in[9], d_in[10], d_in[11],
                       d_in[12], d_in[13], d_in[14], d_in[15], d_in[16],
                       ws, flagp);
    hipLaunchKernelGGL(prep_wic,  dim3(384),  dim3(256), 0, stream, ws);
    hipLaunchKernelGGL(prep_emb,  dim3(2048), dim3(256), 0, stream, ws);
    hipLaunchKernelGGL(prep_xt,   dim3(1024), dim3(256), 0, stream, ws);
    hipLaunchKernelGGL(prep_pack, dim3(480),  dim3(256), 0, stream, ws);
    hipLaunchKernelGGL(prep_gi,   dim3(256),  dim3(256), 0, stream, ws);
    hipLaunchKernelGGL(prep_gipack, dim3(12288), dim3(256), 0, stream, ws);
    hipLaunchKernelGGL(chain_kernel, dim3(NPOUT * NCHUNK), dim3(512), 0, stream,
                       ws, d_out, flagp);
}

// Round 5
// 408.206 us; speedup vs baseline: 4.6246x; 1.6909x over previous
//
#include <hip/hip_runtime.h>
#include <hip/hip_bf16.h>
#include <math.h>

// Problem constants (reference: B,T,D=64, E=HA=HB=128, OUT=1, short=2)
#define B_ 64
#define T_ 64
#define D_ 64
#define PMIN 3        // short+1
#define NPOUT 60      // T-2-short
#define NCHUNK 4      // batch chunks of 16 per prefix

typedef __hip_bfloat16 bf16;
typedef __attribute__((ext_vector_type(8))) short s16x8;
typedef __attribute__((ext_vector_type(4))) float f32x4;

// ---- canonical fp32 input copies (element offsets within OFF_IN) ----
#define CI_X      0
#define CI_WEMB   262144
#define CI_BEMB   270336
#define CI_WIA    270464
#define CI_WHA    319616
#define CI_BIA    368768
#define CI_BHA    369152
#define CI_WIB    369536
#define CI_WHB    418688
#define CI_BIB    467840
#define CI_BHB    468224
#define CI_WA     468608
#define CI_BA     468736
#define CI_WB     468737
#define CI_BB     485121
#define CI_WO     485249
#define CI_BO     485377
#define CI_TOTAL  485378

// ---- workspace layout (fp32 element offsets) ----
#define OFF_EMB   0                      // [t][b][128] fp32
#define OFF_WIC   3670016                // WicT [e][768] fp32
#define OFF_XT    3768320                // xt [t][d][b] fp32
#define OFF_IN    4030464                // canonical fp32 inputs
#define OFF_GIPK  4515844                // bf16 [t][chunk4][w][lane][24]  (1572864 floats)
#define OFF_WPK   6088708                // bf16 [w][nt6][kt][lane][8]     (49152 floats)
#define OFF_BPPK  6137860                // bf16 [w8][kt][lane][8]         (8192 floats)
#define OFF_WMPK  6146052                // bf16 [nt4][kt][lane][8]        (4096 floats)
#define OFF_WALPK 6150148                // bf16 [kt][lane][8]             (1024 floats)
#define OFF_FLAG  6151172

__device__ __forceinline__ float bf2f(unsigned short u) {
    union { float f; unsigned u32; } x; x.u32 = ((unsigned)u) << 16; return x.f;
}
__device__ __forceinline__ unsigned short f2bf(float f) {
    union { float f; unsigned u; } x; x.f = f;
    unsigned r = x.u + 0x7FFFu + ((x.u >> 16) & 1u);
    return (unsigned short)(r >> 16);
}
__device__ __forceinline__ float sigmoidf_(float v) { return 1.f / (1.f + __expf(-v)); }
__device__ __forceinline__ float tanhf_(float v) {
    float e = __expf(-2.f * fabsf(v));
    float t = (1.f - e) / (1.f + e);
    return copysignf(t, v);
}

// ---------------- dtype detection ----------------
__global__ void detect_dtype(const unsigned short* xr, int* flag)
{
    int tid = threadIdx.x;
    int bad = 0;
    for (int i = tid; i < 4096; i += 256) {
        int ex = (xr[i] >> 7) & 0xFF;
        if (ex >= 140) bad++;
    }
    __shared__ int s[256];
    s[tid] = bad;
    __syncthreads();
    for (int st = 128; st > 0; st >>= 1) {
        if (tid < st) s[tid] += s[tid + st];
        __syncthreads();
    }
    if (tid == 0) *flag = (s[0] > 4) ? 1 : 0;
}

// ---------------- canonicalize inputs to fp32 ----------------
__global__ void convert_inputs(const void* p0, const void* p1, const void* p2,
                               const void* p3, const void* p4, const void* p5,
                               const void* p6, const void* p7, const void* p8,
                               const void* p9, const void* p10, const void* p11,
                               const void* p12, const void* p13, const void* p14,
                               const void* p15, const void* p16,
                               float* ws, const int* flagp)
{
    const int flag = *flagp;
    int id = blockIdx.x * 256 + threadIdx.x;
    if (id >= CI_TOTAL) return;
    const int starts[18] = {CI_X, CI_WEMB, CI_BEMB, CI_WIA, CI_WHA, CI_BIA,
                            CI_BHA, CI_WIB, CI_WHB, CI_BIB, CI_BHB, CI_WA,
                            CI_BA, CI_WB, CI_BB, CI_WO, CI_BO, CI_TOTAL};
    const void* ptrs[17] = {p0,p1,p2,p3,p4,p5,p6,p7,p8,p9,p10,p11,p12,p13,p14,p15,p16};
    int k = 0;
    while (id >= starts[k + 1]) k++;
    int li = id - starts[k];
    float v = flag ? ((const float*)ptrs[k])[li]
                   : bf2f(((const unsigned short*)ptrs[k])[li]);
    ws[OFF_IN + id] = v;
}

// ---------------- stage1: WicT [e][768] + emb [t][b][128] ----------------
__global__ void prep_stage1(float* ws)
{
    const float* cin = ws + OFF_IN;
    int id = blockIdx.x * 256 + threadIdx.x;   // 98304 + 524288 = 622592
    if (id < 98304) {
        int e = id / 768, g = id % 768;
        float v = (g < 384) ? cin[CI_WIA + g * 128 + e]
                            : cin[CI_WIB + (g - 384) * 128 + e];
        ws[OFF_WIC + id] = v;
    } else {
        int id2 = id - 98304;
        int e = id2 & 127;
        int tb = id2 >> 7;
        int b = tb & 63, t = tb >> 6;
        const float* xp = cin + CI_X + (b * T_ + t) * D_;
        const float* wp = cin + CI_WEMB + e * D_;
        float acc = cin[CI_BEMB + e];
        #pragma unroll
        for (int d = 0; d < 64; d += 4) {
            f32x4 xv = *(const f32x4*)(xp + d);
            f32x4 wv = *(const f32x4*)(wp + d);
            acc += xv[0]*wv[0] + xv[1]*wv[1] + xv[2]*wv[2] + xv[3]*wv[3];
        }
        ws[OFF_EMB + id2] = acc;
    }
}

// ---------------- stage2: weight packs + xt ----------------
// sections: gh [0,98304) | Wb [98304,114688) | Wm [114688,122880)
//           Wal [122880,124928) | xt [124928,387072)
__global__ void prep_stage2(float* ws)
{
    const float* cin = ws + OFF_IN;
    int id = blockIdx.x * 256 + threadIdx.x;     // 387072 total (1512 blocks)
    if (id < 98304) {                            // gh weights: [w][nt][kt][lane][8]
        unsigned short* wpk = (unsigned short*)(ws + OFF_WPK);
        int w = id / 12288, r1 = id % 12288;
        int nt = r1 / 2048, r2 = r1 % 2048;
        int kt = r2 / 512, r3 = r2 % 512;
        int lane = r3 >> 3, j = r3 & 7;
        int cell = w >> 2, wv = w & 3;
        int gate = nt >> 1, tt = nt & 1;
        int g = gate * 128 + wv * 32 + tt * 16 + (lane & 15);
        int k = kt * 32 + (lane >> 4) * 8 + j;
        wpk[id] = f2bf(cin[(cell ? CI_WHB : CI_WHA) + g * 128 + k]);
    } else if (id < 114688) {                    // Wb: [w][kt][lane][8]
        unsigned short* bpk = (unsigned short*)(ws + OFF_BPPK);
        int id2 = id - 98304;
        int w = id2 / 2048, r = id2 % 2048;
        int kt = r / 512, lane = (r % 512) >> 3, j = r & 7;
        int e = w * 16 + (lane & 15);
        int k = kt * 32 + (lane >> 4) * 8 + j;
        bpk[id2] = f2bf(cin[CI_WB + e * 128 + k]);
    } else if (id < 122880) {                    // Wm: [nt4][kt][lane][8] (8192)
        unsigned short* wmk = (unsigned short*)(ws + OFF_WMPK);
        int id3 = id - 114688;
        int nt = id3 / 2048, r = id3 % 2048;
        int kt = r / 512, lane = (r % 512) >> 3, j = r & 7;
        int d = nt * 16 + (lane & 15);
        int e = kt * 32 + (lane >> 4) * 8 + j;
        wmk[id3] = f2bf(cin[CI_WO + e] * cin[CI_WEMB + e * 64 + d]);
    } else if (id < 124928) {                    // Wa alpha-tile: [kt][lane][8] (2048)
        unsigned short* alk = (unsigned short*)(ws + OFF_WALPK);
        int id4 = id - 122880;
        int kt = id4 / 512, lane = (id4 % 512) >> 3, j = id4 & 7;
        int k = kt * 32 + (lane >> 4) * 8 + j;
        alk[id4] = ((lane & 15) == 0) ? f2bf(cin[CI_WA + k]) : (unsigned short)0;
    } else {                                     // xt [t][d][b] (262144)
        int id5 = id - 124928;
        int b = id5 & 63, d = (id5 >> 6) & 63, t = id5 >> 12;
        ws[OFF_XT + id5] = cin[CI_X + (b * 64 + t) * 64 + d];
    }
}

// ---------------- prep_gi: gi packed bf16 per-lane, bi + bh(r,z) folded ----------------
__global__ void prep_gi(float* ws)
{
    const float* cin = ws + OFF_IN;
    unsigned short* gipk = (unsigned short*)(ws + OFF_GIPK);
    int t = blockIdx.x >> 2;
    int chunk = blockIdx.x & 3;
    int b0 = chunk * 16;
    int tid = threadIdx.x;
    __shared__ __align__(16) float semT[128][16];
    #pragma unroll
    for (int q = 0; q < 8; q++) {
        int idx = tid + q * 256;              // 2048 = 128e x 16r
        int r = idx & 15, e = idx >> 4;
        semT[e][r] = ws[OFF_EMB + (size_t)((t * 64 + b0 + r) * 128) + e];
    }
    __syncthreads();
    float acc[3][16];
    #pragma unroll
    for (int g3 = 0; g3 < 3; g3++)
        #pragma unroll
        for (int r = 0; r < 16; r++) acc[g3][r] = 0.f;
    const float* wic = ws + OFF_WIC;
    for (int e = 0; e < 128; e++) {
        f32x4 h0 = *(const f32x4*)&semT[e][0];
        f32x4 h1 = *(const f32x4*)&semT[e][4];
        f32x4 h2 = *(const f32x4*)&semT[e][8];
        f32x4 h3 = *(const f32x4*)&semT[e][12];
        float hv[16] = {h0[0],h0[1],h0[2],h0[3], h1[0],h1[1],h1[2],h1[3],
                        h2[0],h2[1],h2[2],h2[3], h3[0],h3[1],h3[2],h3[3]};
        float w0 = wic[e * 768 + tid];
        float w1 = wic[e * 768 + tid + 256];
        float w2 = wic[e * 768 + tid + 512];
        #pragma unroll
        for (int r = 0; r < 16; r++) {
            acc[0][r] += hv[r] * w0;
            acc[1][r] += hv[r] * w1;
            acc[2][r] += hv[r] * w2;
        }
    }
    #pragma unroll
    for (int g3 = 0; g3 < 3; g3++) {
        int g = tid + g3 * 256;
        int cellg = g / 384, gr = g % 384;
        int gate = gr / 128, kh = gr % 128;
        int wvp = kh / 32, tt2 = (kh % 32) / 16, l15p = kh % 16;
        int wq = cellg * 4 + wvp;
        float bias = cin[(cellg ? CI_BIB : CI_BIA) + gr];
        if (gate < 2) bias += cin[(cellg ? CI_BHB : CI_BHA) + gr];
        #pragma unroll
        for (int r = 0; r < 16; r++) {
            float v = acc[g3][r] + bias;
            size_t addr = ((((size_t)t * 4 + chunk) * 8 + wq) * 64
                           + (size_t)((r >> 2) * 16 + l15p)) * 24
                          + gate * 8 + tt2 * 4 + (r & 3);
            gipk[addr] = f2bf(v);
        }
    }
}

// ---------------- fused chain kernel (MFMA, 1 barrier/iter) ----------------
// 240 WGs: (prefix p, batch chunk of 16). 512 threads = 8 waves.
// wave w = cell*4 + wv: 6 gate n-tiles (own cell, kh slice wv*32..+32)
//  + 1 betapre tile (e = w*16..+16, A=h_b) + 1 alpha tile (A=h_a, col0=Wa).
// Wh/Wb/Wa B-frags in persistent VGPRs; Wm in LDS. h triple-buffered bf16,
// betbf double-buffered: single __syncthreads per iteration.

__launch_bounds__(512, 2)
__global__ void chain_kernel(const float* ws, void* outv, const int* flagp)
{
    const int p = PMIN + (int)blockIdx.x / NCHUNK;
    const int chunk = (int)blockIdx.x % NCHUNK;
    const int tid = threadIdx.x;
    const int lane = tid & 63;
    const int w = tid >> 6;
    const int cell = w >> 2;
    const int wv = w & 3;
    const int l15 = lane & 15;
    const int quad = lane >> 4;

    __shared__ __align__(16) short hbf[3][2][16][136];   // [buf][cell][row][kh]
    __shared__ __align__(16) short betbf[2][16][136];
    __shared__ __align__(16) short sWm[4][4][64][8];     // [dtile][kt][lane][8]
    __shared__ __align__(16) float cAcc[16][132];
    __shared__ float slFin[16];

    const float* cin = ws + OFF_IN;
    const unsigned short* gipk = (const unsigned short*)(ws + OFF_GIPK);
    const unsigned short* wpk  = (const unsigned short*)(ws + OFF_WPK);
    const unsigned short* bpk  = (const unsigned short*)(ws + OFF_BPPK);
    const unsigned short* alk  = (const unsigned short*)(ws + OFF_WALPK);

    // stage Wm into LDS; zero h buf0 + cAcc
    {
        const int* s2 = (const int*)(ws + OFF_WMPK);
        int* d2 = (int*)&sWm[0][0][0][0];
        for (int i = tid; i < 4096; i += 512) d2[i] = s2[i];
        int* hz = (int*)&hbf[0][0][0][0];
        for (int i = tid; i < 2176; i += 512) hz[i] = 0;
        float* cz = &cAcc[0][0];
        for (int i = tid; i < 2112; i += 512) cz[i] = 0.f;
    }

    // persistent B-fragment registers
    s16x8 wB[6][4];
    #pragma unroll
    for (int nt = 0; nt < 6; nt++)
        #pragma unroll
        for (int kt = 0; kt < 4; kt++)
            wB[nt][kt] = *(const s16x8*)(wpk + (((w * 6 + nt) * 4 + kt) * 64 + lane) * 8);
    s16x8 bBp[4], wAl[4];
    #pragma unroll
    for (int kt = 0; kt < 4; kt++) {
        bBp[kt] = *(const s16x8*)(bpk + ((w * 4 + kt) * 64 + lane) * 8);
        wAl[kt] = *(const s16x8*)(alk + (kt * 64 + lane) * 8);
    }

    // per-lane constants
    const float bhn0 = cin[(cell ? CI_BHB : CI_BHA) + 256 + wv * 32 + l15];
    const float bhn1 = cin[(cell ? CI_BHB : CI_BHA) + 256 + wv * 32 + 16 + l15];
    const float bbE  = cin[CI_BB + w * 16 + l15];
    const float baf  = cin[CI_BA];
    const float bof  = cin[CI_BO];
    const int flag = *flagp;

    float h_old[8];                    // [tt][reg]
    #pragma unroll
    for (int i = 0; i < 8; i++) h_old[i] = 0.f;
    float gAccR[4] = {0.f, 0.f, 0.f, 0.f};
    float sm4[4], sl4[4];
    #pragma unroll
    for (int i = 0; i < 4; i++) { sm4[i] = -INFINITY; sl4[i] = 0.f; }

    // preload gi for it=0 (j=p)
    s16x8 giv[3], givN[3];
    {
        const unsigned short* gp =
            gipk + ((((size_t)p * 4 + chunk) * 8 + w) * 64 + lane) * 24;
        #pragma unroll
        for (int i = 0; i < 3; i++) giv[i] = *(const s16x8*)(gp + i * 8);
    }

    int cur = 0, dbuf = 0;
    __syncthreads();

    for (int it = 0; it <= p + 1; it++) {
        const int j = p - it;
        const int jp = j + 1;
        const bool doGru = (j >= 0);
        const bool doAcc = (it > 0);
        const int nxt = (cur == 2) ? 0 : cur + 1;

        // prefetch next gi
        if (j > 0) {
            const unsigned short* gp =
                gipk + ((((size_t)(j - 1) * 4 + chunk) * 8 + w) * 64 + lane) * 24;
            #pragma unroll
            for (int i = 0; i < 3; i++) givN[i] = *(const s16x8*)(gp + i * 8);
        }
        // prefetch x / emb for this iteration's Phase C
        f32x4 xv, em0, em1;
        if (doAcc) {
            if (w < 4) {
                xv = *(const f32x4*)(ws + OFF_XT + ((size_t)jp * 64 + w * 16 + l15) * 64
                                     + chunk * 16 + quad * 4);
            } else {
                const int row = quad * 4 + (w - 4);
                const float* ep = ws + OFF_EMB
                                  + ((size_t)jp * 64 + chunk * 16 + row) * 128 + l15 * 8;
                em0 = *(const f32x4*)ep;
                em1 = *(const f32x4*)(ep + 4);
            }
        }

        // ---- Phase A: MFMA gates + betapre + alpha from h_it ----
        f32x4 Cg[6], Cbp, Cal;
        #pragma unroll
        for (int nt = 0; nt < 6; nt++) Cg[nt] = (f32x4){0.f,0.f,0.f,0.f};
        Cbp = (f32x4){0.f,0.f,0.f,0.f};
        Cal = (f32x4){0.f,0.f,0.f,0.f};

        #pragma unroll
        for (int kt = 0; kt < 4; kt++) {
            s16x8 aA = *(const s16x8*)&hbf[cur][0][l15][kt * 32 + quad * 8];
            s16x8 aB = *(const s16x8*)&hbf[cur][1][l15][kt * 32 + quad * 8];
            s16x8 aOwn = cell ? aB : aA;
            #pragma unroll
            for (int nt = 0; nt < 6; nt++)
                Cg[nt] = __builtin_amdgcn_mfma_f32_16x16x32_bf16(aOwn, wB[nt][kt], Cg[nt], 0, 0, 0);
            Cbp = __builtin_amdgcn_mfma_f32_16x16x32_bf16(aB, bBp[kt], Cbp, 0, 0, 0);
            Cal = __builtin_amdgcn_mfma_f32_16x16x32_bf16(aA, wAl[kt], Cal, 0, 0, 0);
        }

        // ---- Phase B (no barrier yet) ----
        // online softmax from alpha tile (identical in every wave)
        float sc4[4], we4[4];
        #pragma unroll
        for (int reg = 0; reg < 4; reg++) {
            float sparaw = __shfl(Cal[reg], lane & 48);   // col 0 of my quad's rows
            float spav = 0.5f * sparaw + baf;
            if (doAcc) {
                float mnew = fmaxf(sm4[reg], spav);
                sc4[reg] = __expf(sm4[reg] - mnew);
                we4[reg] = __expf(spav - mnew);
                sl4[reg] = sl4[reg] * sc4[reg] + we4[reg];
                sm4[reg] = mnew;
            }
        }

        // GRU nonlinearity in-register; h_{it+1} -> hbf[nxt]
        if (doGru) {
            #pragma unroll
            for (int tt = 0; tt < 2; tt++)
                #pragma unroll
                for (int reg = 0; reg < 4; reg++) {
                    float gir = bf2f((unsigned short)giv[0][tt * 4 + reg]);
                    float giz = bf2f((unsigned short)giv[1][tt * 4 + reg]);
                    float gin = bf2f((unsigned short)giv[2][tt * 4 + reg]);
                    float ghr = Cg[0 + tt][reg];
                    float ghz = Cg[2 + tt][reg];
                    float ghn = Cg[4 + tt][reg] + (tt ? bhn1 : bhn0);
                    float ho  = h_old[tt * 4 + reg];
                    float rr = sigmoidf_(gir + ghr);
                    float zz = sigmoidf_(giz + ghz);
                    float nn = tanhf_(gin + rr * ghn);
                    float hn = (1.f - zz) * nn + zz * ho;
                    h_old[tt * 4 + reg] = hn;
                    hbf[nxt][cell][quad * 4 + reg][wv * 32 + tt * 16 + l15] = (short)f2bf(hn);
                }
        }
        // beta = tanh(0.5*betapre + bb) -> betbf[dbuf]
        #pragma unroll
        for (int reg = 0; reg < 4; reg++) {
            float bv = tanhf_(0.5f * Cbp[reg] + bbE);
            betbf[dbuf][quad * 4 + reg][w * 16 + l15] = (short)f2bf(bv);
        }

        __syncthreads();   // the ONE barrier

        // ---- Phase C: attention accumulation (scan step it-1) ----
        if (doAcc) {
            if (w < 4) {
                // e_chain = beta @ Wm  (d in [w*16, w*16+16))
                f32x4 ec = (f32x4){0.f,0.f,0.f,0.f};
                #pragma unroll
                for (int kt = 0; kt < 4; kt++) {
                    s16x8 a = *(const s16x8*)&betbf[dbuf][l15][kt * 32 + quad * 8];
                    s16x8 bw = *(const s16x8*)&sWm[w][kt][lane][0];
                    ec = __builtin_amdgcn_mfma_f32_16x16x32_bf16(a, bw, ec, 0, 0, 0);
                }
                #pragma unroll
                for (int reg = 0; reg < 4; reg++)
                    gAccR[reg] = gAccR[reg] * sc4[reg] + we4[reg] * ec[reg] * xv[reg];
            } else {
                const int row = quad * 4 + (w - 4);
                const float sc = sc4[w - 4], we = we4[w - 4];
                s16x8 bets = *(const s16x8*)&betbf[dbuf][row][l15 * 8];
                float* cp = &cAcc[row][l15 * 8];
                #pragma unroll
                for (int v = 0; v < 4; v++)
                    cp[v] = cp[v] * sc + we * bf2f((unsigned short)bets[v]) * em0[v];
                #pragma unroll
                for (int v = 0; v < 4; v++)
                    cp[4 + v] = cp[4 + v] * sc + we * bf2f((unsigned short)bets[4 + v]) * em1[v];
            }
        }

        if (j > 0) { giv[0] = givN[0]; giv[1] = givN[1]; giv[2] = givN[2]; }
        cur = nxt;
        dbuf ^= 1;
    }

    // ---- epilogue ----
    if (w == 7 && l15 == 0) {
        #pragma unroll
        for (int reg = 0; reg < 4; reg++) slFin[quad * 4 + reg] = sl4[reg];
    }
    __syncthreads();

    if (tid < 256) {   // pred = (c/l) . Wo + bo
        int r = tid >> 4, ks = tid & 15;
        float part = 0.f;
        #pragma unroll
        for (int t2 = 0; t2 < 8; t2++) {
            int e = ks + t2 * 16;
            part += cAcc[r][e] * cin[CI_WO + e];
        }
        part += __shfl_xor(part, 1);
        part += __shfl_xor(part, 2);
        part += __shfl_xor(part, 4);
        part += __shfl_xor(part, 8);
        if (ks == 0) {
            int bglob = chunk * 16 + r;
            float pr = part / slFin[r] + bof;
            size_t oi = (size_t)bglob * NPOUT + (p - PMIN);
            if (flag) ((float*)outv)[oi] = pr;
            else      ((bf16*)outv)[oi] = __float2bfloat16(pr);
        }
    }
    if (w < 4) {   // weight = g/l/(p+1)
        const float invt = 1.f / (float)(p + 1);
        #pragma unroll
        for (int reg = 0; reg < 4; reg++) {
            int row = quad * 4 + reg;
            int bglob = chunk * 16 + row;
            float gv = gAccR[reg] / slFin[row] * invt;
            size_t oi = (size_t)B_ * NPOUT
                      + ((size_t)bglob * NPOUT + (p - PMIN)) * 64 + w * 16 + l15;
            if (flag) ((float*)outv)[oi] = gv;
            else      ((bf16*)outv)[oi] = __float2bfloat16(gv);
        }
    }
}

// ---------------- launch ----------------
extern "C" void kernel_launch(void* const* d_in, const int* in_sizes, int n_in,
                              void* d_out, int out_size, void* d_ws, size_t ws_size,
                              hipStream_t stream)
{
    float* ws = (float*)d_ws;
    int* flagp = (int*)(ws + OFF_FLAG);

    hipLaunchKernelGGL(detect_dtype, dim3(1), dim3(256), 0, stream,
                       (const unsigned short*)d_in[0], flagp);
    hipLaunchKernelGGL(convert_inputs, dim3((CI_TOTAL + 255) / 256), dim3(256), 0, stream,
                       d_in[0], d_in[1], d_in[2], d_in[3], d_in[4], d_in[5],
                       d_in[6], d_in[7], d_in[8], d_in[9], d_in[10], d_in[11],
                       d_in[12], d_in[13], d_in[14], d_in[15], d_in[16],
                       ws, flagp);
    hipLaunchKernelGGL(prep_stage1, dim3(2432), dim3(256), 0, stream, ws);
    hipLaunchKernelGGL(prep_stage2, dim3(1512), dim3(256), 0, stream, ws);
    hipLaunchKernelGGL(prep_gi,     dim3(256),  dim3(256), 0, stream, ws);
    hipLaunchKernelGGL(chain_kernel, dim3(NPOUT * NCHUNK), dim3(512), 0, stream,
                       ws, d_out, flagp);
}

// Round 6
// 377.877 us; speedup vs baseline: 4.9958x; 1.0803x over previous
//
#include <hip/hip_runtime.h>
#include <hip/hip_bf16.h>
#include <math.h>

// Problem constants (reference: B,T,D=64, E=HA=HB=128, OUT=1, short=2)
#define B_ 64
#define T_ 64
#define D_ 64
#define PMIN 3        // short+1
#define NPOUT 60      // T-2-short
#define NCHUNK 4      // batch chunks of 16 per prefix

typedef __hip_bfloat16 bf16;
typedef __attribute__((ext_vector_type(4))) short s16x4;
typedef __attribute__((ext_vector_type(8))) short s16x8;
typedef __attribute__((ext_vector_type(4))) float f32x4;

// ---- canonical fp32 input copies (element offsets within OFF_IN) ----
#define CI_X      0
#define CI_WEMB   262144
#define CI_BEMB   270336
#define CI_WIA    270464
#define CI_WHA    319616
#define CI_BIA    368768
#define CI_BHA    369152
#define CI_WIB    369536
#define CI_WHB    418688
#define CI_BIB    467840
#define CI_BHB    468224
#define CI_WA     468608
#define CI_BA     468736
#define CI_WB     468737
#define CI_BB     485121
#define CI_WO     485249
#define CI_BO     485377
#define CI_TOTAL  485378

// ---- workspace layout (fp32 element offsets) ----
#define OFF_EMB   0                      // [t][b][128] fp32
#define OFF_WIC   524288                 // WicT [e][768] fp32
#define OFF_XT    622592                 // xt [t][d][b] fp32
#define OFF_IN    884736                 // canonical fp32 inputs
#define OFF_GIPK  1370114                // bf16 [t][chunk4][w][lane][24]
#define OFF_WPK   2942978                // bf16 [w][nt6][kt][lane][8] (pi-k)
#define OFF_BPPK  2992130                // bf16 [w8][kt][lane][8]     (pi-k)
#define OFF_WMPK  3000322                // bf16 [nt4][kt][lane][8]    (true e)
#define OFF_WALPK 3004418                // bf16 [kt][lane][8]         (pi-k)
#define OFF_FLAG  3005442

__device__ __forceinline__ float bf2f(unsigned short u) {
    union { float f; unsigned u32; } x; x.u32 = ((unsigned)u) << 16; return x.f;
}
__device__ __forceinline__ unsigned short f2bf(float f) {
    union { float f; unsigned u; } x; x.f = f;
    unsigned r = x.u + 0x7FFFu + ((x.u >> 16) & 1u);
    return (unsigned short)(r >> 16);
}
__device__ __forceinline__ float sigmoidf_(float v) { return 1.f / (1.f + __expf(-v)); }
__device__ __forceinline__ float tanhf_(float v) {
    float e = __expf(-2.f * fabsf(v));
    float t = (1.f - e) / (1.f + e);
    return copysignf(t, v);
}
// k-dimension permutation: stored slot s -> true index (pairs (l,t) adjacent)
__device__ __forceinline__ int kpi(int s) {
    return (s & ~31) | ((s & 1) << 4) | ((s & 31) >> 1);
}
__device__ __forceinline__ s16x8 ldA(const short* p) {   // 8B-aligned 16-byte LDS read
    s16x4 lo = *(const s16x4*)p;
    s16x4 hi = *(const s16x4*)(p + 4);
    return __builtin_shufflevector(lo, hi, 0, 1, 2, 3, 4, 5, 6, 7);
}

// ---------------- dtype detection ----------------
__global__ void detect_dtype(const unsigned short* xr, int* flag)
{
    int tid = threadIdx.x;
    int bad = 0;
    for (int i = tid; i < 4096; i += 256) {
        int ex = (xr[i] >> 7) & 0xFF;
        if (ex >= 140) bad++;
    }
    __shared__ int s[256];
    s[tid] = bad;
    __syncthreads();
    for (int st = 128; st > 0; st >>= 1) {
        if (tid < st) s[tid] += s[tid + st];
        __syncthreads();
    }
    if (tid == 0) *flag = (s[0] > 4) ? 1 : 0;
}

// ---------------- canonicalize inputs (block-uniform tensor select) ----------------
__global__ void convert_inputs(const void* p0, const void* p1, const void* p2,
                               const void* p3, const void* p4, const void* p5,
                               const void* p6, const void* p7, const void* p8,
                               const void* p9, const void* p10, const void* p11,
                               const void* p12, const void* p13, const void* p14,
                               const void* p15, const void* p16,
                               float* ws, const int* flagp)
{
    // per-tensor block counts (ceil(n/256)); total 1902 blocks
    const int bc[17]     = {1024, 32, 1, 192, 192, 2, 2, 192, 192, 2, 2, 1, 1, 64, 1, 1, 1};
    const int sizes[17]  = {262144, 8192, 128, 49152, 49152, 384, 384, 49152, 49152,
                            384, 384, 128, 1, 16384, 128, 128, 1};
    const int starts[17] = {CI_X, CI_WEMB, CI_BEMB, CI_WIA, CI_WHA, CI_BIA, CI_BHA,
                            CI_WIB, CI_WHB, CI_BIB, CI_BHB, CI_WA, CI_BA, CI_WB,
                            CI_BB, CI_WO, CI_BO};
    int b = blockIdx.x, k = 0;
    while (b >= bc[k]) { b -= bc[k]; k++; }          // uniform scalar loop
    int li = b * 256 + threadIdx.x;
    if (li >= sizes[k]) return;
    const void* p;
    switch (k) {                                      // uniform -> scalar select
        case 0: p = p0; break;  case 1: p = p1; break;  case 2: p = p2; break;
        case 3: p = p3; break;  case 4: p = p4; break;  case 5: p = p5; break;
        case 6: p = p6; break;  case 7: p = p7; break;  case 8: p = p8; break;
        case 9: p = p9; break;  case 10: p = p10; break; case 11: p = p11; break;
        case 12: p = p12; break; case 13: p = p13; break; case 14: p = p14; break;
        case 15: p = p15; break; default: p = p16; break;
    }
    float v;
    if (*flagp) v = ((const float*)p)[li];
    else        v = bf2f(((const unsigned short*)p)[li]);
    ws[OFF_IN + starts[k] + li] = v;
}

// ---------------- prep_all: WicT + emb + xt + all weight packs ----------------
// sections: wic [0,98304) | emb [98304,622592) | xt [622592,884736)
//           wpk [884736,983040) | bppk [983040,999424) | wmpk [999424,1007616)
//           walpk [1007616,1009664)   -> 3944 blocks x 256
__global__ void prep_all(float* ws)
{
    const float* cin = ws + OFF_IN;
    int id = blockIdx.x * 256 + threadIdx.x;
    if (id < 98304) {                                 // WicT [e][768]
        int e = id / 768, g = id % 768;
        float v = (g < 384) ? cin[CI_WIA + g * 128 + e]
                            : cin[CI_WIB + (g - 384) * 128 + e];
        ws[OFF_WIC + id] = v;
    } else if (id < 622592) {                         // emb [t][b][128]
        int id2 = id - 98304;
        int e = id2 & 127;
        int tb = id2 >> 7;
        int b = tb & 63, t = tb >> 6;
        const float* xp = cin + CI_X + (b * T_ + t) * D_;
        const float* wp = cin + CI_WEMB + e * D_;
        float acc = cin[CI_BEMB + e];
        #pragma unroll
        for (int d = 0; d < 64; d += 4) {
            f32x4 xv = *(const f32x4*)(xp + d);
            f32x4 wv = *(const f32x4*)(wp + d);
            acc += xv[0]*wv[0] + xv[1]*wv[1] + xv[2]*wv[2] + xv[3]*wv[3];
        }
        ws[OFF_EMB + id2] = acc;
    } else if (id < 884736) {                         // xt [t][d][b]
        int id5 = id - 622592;
        int b = id5 & 63, d = (id5 >> 6) & 63, t = id5 >> 12;
        ws[OFF_XT + id5] = cin[CI_X + (b * 64 + t) * 64 + d];
    } else if (id < 983040) {                         // gh weights (pi-k)
        unsigned short* wpk = (unsigned short*)(ws + OFF_WPK);
        int id3 = id - 884736;
        int w = id3 / 12288, r1 = id3 % 12288;
        int nt = r1 / 2048, r2 = r1 % 2048;
        int kt = r2 / 512, r3 = r2 % 512;
        int lane = r3 >> 3, j = r3 & 7;
        int cell = w >> 2, wv = w & 3;
        int gate = nt >> 1, tt = nt & 1;
        int g = gate * 128 + wv * 32 + tt * 16 + (lane & 15);
        int k = kpi(kt * 32 + (lane >> 4) * 8 + j);
        wpk[id3] = f2bf(cin[(cell ? CI_WHB : CI_WHA) + g * 128 + k]);
    } else if (id < 999424) {                         // Wb (pi-k)
        unsigned short* bpk = (unsigned short*)(ws + OFF_BPPK);
        int id4 = id - 983040;
        int w = id4 / 2048, r = id4 % 2048;
        int kt = r / 512, lane = (r % 512) >> 3, j = r & 7;
        int e = w * 16 + (lane & 15);
        int k = kpi(kt * 32 + (lane >> 4) * 8 + j);
        bpk[id4] = f2bf(cin[CI_WB + e * 128 + k]);
    } else if (id < 1007616) {                        // Wm (true e)
        unsigned short* wmk = (unsigned short*)(ws + OFF_WMPK);
        int id6 = id - 999424;
        int nt = id6 / 2048, r = id6 % 2048;
        int kt = r / 512, lane = (r % 512) >> 3, j = r & 7;
        int d = nt * 16 + (lane & 15);
        int e = kt * 32 + (lane >> 4) * 8 + j;
        wmk[id6] = f2bf(cin[CI_WO + e] * cin[CI_WEMB + e * 64 + d]);
    } else {                                          // Wa alpha tile (pi-k)
        unsigned short* alk = (unsigned short*)(ws + OFF_WALPK);
        int id7 = id - 1007616;
        int kt = id7 / 512, lane = (id7 % 512) >> 3, j = id7 & 7;
        int k = kpi(kt * 32 + (lane >> 4) * 8 + j);
        alk[id7] = ((lane & 15) == 0) ? f2bf(cin[CI_WA + k]) : (unsigned short)0;
    }
}

// ---------------- prep_gi: gi packed bf16 per-lane, bi + bh(r,z) folded ----------------
__global__ void prep_gi(float* ws)
{
    const float* cin = ws + OFF_IN;
    unsigned short* gipk = (unsigned short*)(ws + OFF_GIPK);
    int t = blockIdx.x >> 2;
    int chunk = blockIdx.x & 3;
    int b0 = chunk * 16;
    int tid = threadIdx.x;
    __shared__ __align__(16) float semT[128][16];
    #pragma unroll
    for (int q = 0; q < 8; q++) {
        int idx = tid + q * 256;
        int r = idx & 15, e = idx >> 4;
        semT[e][r] = ws[OFF_EMB + (size_t)((t * 64 + b0 + r) * 128) + e];
    }
    __syncthreads();
    float acc[3][16];
    #pragma unroll
    for (int g3 = 0; g3 < 3; g3++)
        #pragma unroll
        for (int r = 0; r < 16; r++) acc[g3][r] = 0.f;
    const float* wic = ws + OFF_WIC;
    for (int e = 0; e < 128; e++) {
        f32x4 h0 = *(const f32x4*)&semT[e][0];
        f32x4 h1 = *(const f32x4*)&semT[e][4];
        f32x4 h2 = *(const f32x4*)&semT[e][8];
        f32x4 h3 = *(const f32x4*)&semT[e][12];
        float hv[16] = {h0[0],h0[1],h0[2],h0[3], h1[0],h1[1],h1[2],h1[3],
                        h2[0],h2[1],h2[2],h2[3], h3[0],h3[1],h3[2],h3[3]};
        float w0 = wic[e * 768 + tid];
        float w1 = wic[e * 768 + tid + 256];
        float w2 = wic[e * 768 + tid + 512];
        #pragma unroll
        for (int r = 0; r < 16; r++) {
            acc[0][r] += hv[r] * w0;
            acc[1][r] += hv[r] * w1;
            acc[2][r] += hv[r] * w2;
        }
    }
    #pragma unroll
    for (int g3 = 0; g3 < 3; g3++) {
        int g = tid + g3 * 256;
        int cellg = g / 384, gr = g % 384;
        int gate = gr / 128, kh = gr % 128;
        int wvp = kh / 32, tt2 = (kh % 32) / 16, l15p = kh % 16;
        int wq = cellg * 4 + wvp;
        float bias = cin[(cellg ? CI_BIB : CI_BIA) + gr];
        if (gate < 2) bias += cin[(cellg ? CI_BHB : CI_BHA) + gr];
        #pragma unroll
        for (int r = 0; r < 16; r++) {
            float v = acc[g3][r] + bias;
            size_t addr = ((((size_t)t * 4 + chunk) * 8 + wq) * 64
                           + (size_t)((r >> 2) * 16 + l15p)) * 24
                          + gate * 8 + tt2 * 4 + (r & 3);
            gipk[addr] = f2bf(v);
        }
    }
}

// ---------------- fused chain kernel ----------------
// 240 WGs: (prefix p, batch chunk of 16). 512 threads = 8 waves.
// wave w = cell*4+wv: 6 gate n-tiles + 1 betapre tile; wave 7 also alpha tile.
// No online max (spa bounded): direct exp accumulation. cAcc in registers.
// k-dim pi-packed in LDS h so GRU writes are packed b32; stride 132 kills
// bank conflicts. One barrier per iteration.

__launch_bounds__(512, 2)
__global__ void chain_kernel(const float* ws, void* outv, const int* flagp,
                             const void* p_bha, const void* p_bhb,
                             const void* p_bb, const void* p_ba,
                             const void* p_bo, const void* p_wo)
{
    const int p = PMIN + (int)blockIdx.x / NCHUNK;
    const int chunk = (int)blockIdx.x % NCHUNK;
    const int tid = threadIdx.x;
    const int lane = tid & 63;
    const int w = tid >> 6;
    const int cell = w >> 2;
    const int wv = w & 3;
    const int l15 = lane & 15;
    const int quad = lane >> 4;

    __shared__ __align__(16) short hbf[2][2][16][132];   // [buf][cell][row][m] pi-packed k
    __shared__ __align__(16) short betbf[2][16][132];    // true-e order
    __shared__ __align__(16) short sWm[4][4][64][8];
    __shared__ float spaLds[2][16];

    const unsigned short* gipk = (const unsigned short*)(ws + OFF_GIPK);
    const unsigned short* wpk  = (const unsigned short*)(ws + OFF_WPK);
    const unsigned short* bpk  = (const unsigned short*)(ws + OFF_BPPK);
    const unsigned short* alk  = (const unsigned short*)(ws + OFF_WALPK);
    const int flag = *flagp;

    {   // stage Wm; zero h buf0
        const int* s2 = (const int*)(ws + OFF_WMPK);
        int* d2 = (int*)&sWm[0][0][0][0];
        for (int i = tid; i < 4096; i += 512) d2[i] = s2[i];
        int* hz = (int*)&hbf[0][0][0][0];
        for (int i = tid; i < 2112; i += 512) hz[i] = 0;
    }

    // persistent B-fragment registers
    s16x8 wB[6][4];
    #pragma unroll
    for (int nt = 0; nt < 6; nt++)
        #pragma unroll
        for (int kt = 0; kt < 4; kt++)
            wB[nt][kt] = *(const s16x8*)(wpk + (((w * 6 + nt) * 4 + kt) * 64 + lane) * 8);
    s16x8 bBp[4], wAl[4];
    #pragma unroll
    for (int kt = 0; kt < 4; kt++) {
        bBp[kt] = *(const s16x8*)(bpk + ((w * 4 + kt) * 64 + lane) * 8);
        wAl[kt] = *(const s16x8*)(alk + (kt * 64 + lane) * 8);
    }

    // per-lane constants (uniform flag branch; no speculative cross-dtype loads)
    float bhn0, bhn1, bbE, baf, bof;
    if (flag) {
        const float* bh = (const float*)(cell ? p_bhb : p_bha);
        bhn0 = bh[256 + wv * 32 + l15];
        bhn1 = bh[256 + wv * 32 + 16 + l15];
        bbE = ((const float*)p_bb)[w * 16 + l15];
        baf = ((const float*)p_ba)[0];
        bof = ((const float*)p_bo)[0];
    } else {
        const unsigned short* bh = (const unsigned short*)(cell ? p_bhb : p_bha);
        bhn0 = bf2f(bh[256 + wv * 32 + l15]);
        bhn1 = bf2f(bh[256 + wv * 32 + 16 + l15]);
        bbE = bf2f(((const unsigned short*)p_bb)[w * 16 + l15]);
        baf = bf2f(((const unsigned short*)p_ba)[0]);
        bof = bf2f(((const unsigned short*)p_bo)[0]);
    }

    float h_old[8];
    #pragma unroll
    for (int i = 0; i < 8; i++) h_old[i] = 0.f;
    float gAccR[4] = {0.f, 0.f, 0.f, 0.f};   // waves 0-3
    float cAccR[8] = {0.f, 0.f, 0.f, 0.f, 0.f, 0.f, 0.f, 0.f};  // waves 4-7
    float sl4[4] = {0.f, 0.f, 0.f, 0.f};
    float slB = 0.f;

    s16x8 giv[3], givN[3];
    {
        const unsigned short* gp =
            gipk + ((((size_t)p * 4 + chunk) * 8 + w) * 64 + lane) * 24;
        #pragma unroll
        for (int i = 0; i < 3; i++) giv[i] = *(const s16x8*)(gp + i * 8);
    }

    __syncthreads();

    for (int it = 0; it <= p + 1; it++) {
        const int j = p - it;
        const int jp = j + 1;
        const bool doGru = (j >= 0);
        const bool doAcc = (it > 0);
        const int cur = it & 1;
        const int nxt = cur ^ 1;
        const int dbuf = it & 1;

        // prefetch next gi
        if (j > 0) {
            const unsigned short* gp =
                gipk + ((((size_t)(j - 1) * 4 + chunk) * 8 + w) * 64 + lane) * 24;
            #pragma unroll
            for (int i = 0; i < 3; i++) givN[i] = *(const s16x8*)(gp + i * 8);
        }
        // prefetch x / emb for Phase C
        f32x4 xv, em0, em1;
        if (doAcc) {
            if (w < 4) {
                xv = *(const f32x4*)(ws + OFF_XT + ((size_t)jp * 64 + w * 16 + l15) * 64
                                     + chunk * 16 + quad * 4);
            } else {
                const int row = quad * 4 + (w - 4);
                const float* ep = ws + OFF_EMB
                                  + ((size_t)jp * 64 + chunk * 16 + row) * 128 + l15 * 8;
                em0 = *(const f32x4*)ep;
                em1 = *(const f32x4*)(ep + 4);
            }
        }

        // ---- Phase A: MFMA gates + betapre (+ alpha on wave 7) ----
        f32x4 Cg[6], Cbp, Cal;
        #pragma unroll
        for (int nt = 0; nt < 6; nt++) Cg[nt] = (f32x4){0.f,0.f,0.f,0.f};
        Cbp = (f32x4){0.f,0.f,0.f,0.f};
        Cal = (f32x4){0.f,0.f,0.f,0.f};

        #pragma unroll
        for (int kt = 0; kt < 4; kt++) {
            s16x8 aA = ldA(&hbf[cur][0][l15][kt * 32 + quad * 8]);
            s16x8 aB = ldA(&hbf[cur][1][l15][kt * 32 + quad * 8]);
            s16x8 aOwn = cell ? aB : aA;
            #pragma unroll
            for (int nt = 0; nt < 6; nt++)
                Cg[nt] = __builtin_amdgcn_mfma_f32_16x16x32_bf16(aOwn, wB[nt][kt], Cg[nt], 0, 0, 0);
            Cbp = __builtin_amdgcn_mfma_f32_16x16x32_bf16(aB, bBp[kt], Cbp, 0, 0, 0);
            if (w == 7)
                Cal = __builtin_amdgcn_mfma_f32_16x16x32_bf16(aA, wAl[kt], Cal, 0, 0, 0);
        }

        // ---- Phase B ----
        if (w == 7 && l15 == 0) {     // spa for scan step it-1 (state S_it)
            #pragma unroll
            for (int reg = 0; reg < 4; reg++)
                spaLds[dbuf][quad * 4 + reg] = fminf(0.5f * Cal[reg] + baf, 60.f);
        }
        if (doGru) {                  // GRU in-register; packed b32 h write
            #pragma unroll
            for (int reg = 0; reg < 4; reg++) {
                float hn2[2];
                #pragma unroll
                for (int tt = 0; tt < 2; tt++) {
                    float gir = bf2f((unsigned short)giv[0][tt * 4 + reg]);
                    float giz = bf2f((unsigned short)giv[1][tt * 4 + reg]);
                    float gin = bf2f((unsigned short)giv[2][tt * 4 + reg]);
                    float ghr = Cg[0 + tt][reg];
                    float ghz = Cg[2 + tt][reg];
                    float ghn = Cg[4 + tt][reg] + (tt ? bhn1 : bhn0);
                    float ho  = h_old[tt * 4 + reg];
                    float rr = sigmoidf_(gir + ghr);
                    float zz = sigmoidf_(giz + ghz);
                    float nn = tanhf_(gin + rr * ghn);
                    float hv2 = (1.f - zz) * nn + zz * ho;
                    h_old[tt * 4 + reg] = hv2;
                    hn2[tt] = hv2;
                }
                unsigned pk = (unsigned)f2bf(hn2[0]) | ((unsigned)f2bf(hn2[1]) << 16);
                *(unsigned*)&hbf[nxt][cell][quad * 4 + reg][wv * 32 + l15 * 2] = pk;
            }
        }
        // beta = tanh(0.5*betapre + bb) (true-e order)
        #pragma unroll
        for (int reg = 0; reg < 4; reg++) {
            float bv = tanhf_(0.5f * Cbp[reg] + bbE);
            betbf[dbuf][quad * 4 + reg][w * 16 + l15] = (short)f2bf(bv);
        }

        __syncthreads();   // the ONE barrier

        // ---- Phase C: attention accumulation (scan step it-1) ----
        if (doAcc) {
            if (w < 4) {
                f32x4 ec = (f32x4){0.f,0.f,0.f,0.f};
                #pragma unroll
                for (int kt = 0; kt < 4; kt++) {
                    s16x8 a = ldA(&betbf[dbuf][l15][kt * 32 + quad * 8]);
                    s16x8 bw = *(const s16x8*)&sWm[w][kt][lane][0];
                    ec = __builtin_amdgcn_mfma_f32_16x16x32_bf16(a, bw, ec, 0, 0, 0);
                }
                #pragma unroll
                for (int reg = 0; reg < 4; reg++) {
                    float we = __expf(spaLds[dbuf][quad * 4 + reg]);
                    sl4[reg] += we;
                    gAccR[reg] += we * ec[reg] * xv[reg];
                }
            } else {
                const int row = quad * 4 + (w - 4);
                float we = __expf(spaLds[dbuf][row]);
                slB += we;
                const short* bp2 = &betbf[dbuf][row][l15 * 8];
                s16x4 blo = *(const s16x4*)bp2;
                s16x4 bhi = *(const s16x4*)(bp2 + 4);
                #pragma unroll
                for (int v = 0; v < 4; v++)
                    cAccR[v] += we * bf2f((unsigned short)blo[v]) * em0[v];
                #pragma unroll
                for (int v = 0; v < 4; v++)
                    cAccR[4 + v] += we * bf2f((unsigned short)bhi[v]) * em1[v];
            }
        }

        if (j > 0) { giv[0] = givN[0]; giv[1] = givN[1]; giv[2] = givN[2]; }
    }

    // ---- epilogue ----
    if (w >= 4) {       // pred = (c . Wo)/sl + bo   (rows quad*4 + (w-4))
        const int row = quad * 4 + (w - 4);
        float wo8[8];
        if (flag) {
            const float* wp = (const float*)p_wo + l15 * 8;
            #pragma unroll
            for (int v = 0; v < 8; v++) wo8[v] = wp[v];
        } else {
            const unsigned short* wp = (const unsigned short*)p_wo + l15 * 8;
            #pragma unroll
            for (int v = 0; v < 8; v++) wo8[v] = bf2f(wp[v]);
        }
        float part = 0.f;
        #pragma unroll
        for (int v = 0; v < 8; v++) part += cAccR[v] * wo8[v];
        part += __shfl_xor(part, 1);
        part += __shfl_xor(part, 2);
        part += __shfl_xor(part, 4);
        part += __shfl_xor(part, 8);
        if (l15 == 0) {
            int bglob = chunk * 16 + row;
            float pr = part / slB + bof;
            size_t oi = (size_t)bglob * NPOUT + (p - PMIN);
            if (flag) ((float*)outv)[oi] = pr;
            else      ((bf16*)outv)[oi] = __float2bfloat16(pr);
        }
    } else {            // weight = g/sl/(p+1)
        const float invt = 1.f / (float)(p + 1);
        #pragma unroll
        for (int reg = 0; reg < 4; reg++) {
            int row = quad * 4 + reg;
            int bglob = chunk * 16 + row;
            float gv = gAccR[reg] / sl4[reg] * invt;
            size_t oi = (size_t)B_ * NPOUT
                      + ((size_t)bglob * NPOUT + (p - PMIN)) * 64 + w * 16 + l15;
            if (flag) ((float*)outv)[oi] = gv;
            else      ((bf16*)outv)[oi] = __float2bfloat16(gv);
        }
    }
}

// ---------------- launch ----------------
extern "C" void kernel_launch(void* const* d_in, const int* in_sizes, int n_in,
                              void* d_out, int out_size, void* d_ws, size_t ws_size,
                              hipStream_t stream)
{
    float* ws = (float*)d_ws;
    int* flagp = (int*)(ws + OFF_FLAG);

    hipLaunchKernelGGL(detect_dtype, dim3(1), dim3(256), 0, stream,
                       (const unsigned short*)d_in[0], flagp);
    hipLaunchKernelGGL(convert_inputs, dim3(1902), dim3(256), 0, stream,
                       d_in[0], d_in[1], d_in[2], d_in[3], d_in[4], d_in[5],
                       d_in[6], d_in[7], d_in[8], d_in[9], d_in[10], d_in[11],
                       d_in[12], d_in[13], d_in[14], d_in[15], d_in[16],
                       ws, flagp);
    hipLaunchKernelGGL(prep_all, dim3(3944), dim3(256), 0, stream, ws);
    hipLaunchKernelGGL(prep_gi,  dim3(256),  dim3(256), 0, stream, ws);
    hipLaunchKernelGGL(chain_kernel, dim3(NPOUT * NCHUNK), dim3(512), 0, stream,
                       ws, d_out, flagp,
                       d_in[6], d_in[10], d_in[14], d_in[12], d_in[16], d_in[15]);
}